// Round 7
// baseline (556.255 us; speedup 1.0000x reference)
//
#include <hip/hip_runtime.h>
#include <hip/hip_cooperative_groups.h>
#include <math.h>

namespace cg = cooperative_groups;

#define B_ 4
#define N_ 2048
#define D_ 512
#define H_ 8
// NORM * log2(e): scores pre-scaled so softmax uses exp2 directly.
#define NORM2_ 0.18033688011112042f

typedef __attribute__((ext_vector_type(8))) short short8;   // 8 bf16 (4 VGPRs)
typedef __attribute__((ext_vector_type(4))) float f32x4;    // MFMA C/D
#define MFMA16(a, b, c) __builtin_amdgcn_mfma_f32_16x16x32_bf16(a, b, c, 0, 0, 0)
#define EXP2(x) __builtin_amdgcn_exp2f(x)

static __device__ __forceinline__ ushort f2bf(float x) {
  union { float f; uint32_t u; } v; v.f = x;
  const uint32_t r = v.u + 0x7fffu + ((v.u >> 16) & 1u);  // RNE
  return (ushort)(r >> 16);
}

// async global->LDS, 16B per lane. LDS dest must be wave-uniform base + lane*16.
static __device__ __forceinline__ void async16(ushort* lds, const ushort* g) {
  __builtin_amdgcn_global_load_lds(
      (const __attribute__((address_space(1))) uint32_t*)g,
      (__attribute__((address_space(3))) uint32_t*)lds, 16, 0, 0);
}

// ---- 64x64-tile, K=512 gemm helper: C = X @ W^T (NZ outputs share the X tile) ----
template <int NZ, int F32OUT>
static __device__ __forceinline__ void gemm64(const ushort* __restrict__ X,
                                              const ushort* __restrict__ Wa,
                                              const ushort* __restrict__ Wb,
                                              void* __restrict__ Ca,
                                              void* __restrict__ Cb, float sA,
                                              int tt, int nf, char* smem, int t) {
  ushort(*Xs)[64] = (ushort(*)[64])smem;
  ushort(*WsA)[64] = (ushort(*)[64])(smem + 8192);
  ushort(*WsB)[64] = (ushort(*)[64])(smem + 16384);
  const int w = t >> 6, lane = t & 63, quad = lane >> 4, c = lane & 15;
  const int m0 = tt * 64, n0 = nf * 64;
  f32x4 acc[NZ][4];
#pragma unroll
  for (int z = 0; z < NZ; ++z)
#pragma unroll
    for (int i = 0; i < 4; ++i) acc[z][i] = (f32x4){0.f, 0.f, 0.f, 0.f};

  for (int k0 = 0; k0 < D_; k0 += 64) {
    __syncthreads();
#pragma unroll
    for (int p = 0; p < 2; ++p) {
      const int id = t + p * 256;
      const int row = id >> 3, lch = id & 7, gch = lch ^ (row & 7);
      async16(&Xs[row][lch * 8], X + (size_t)(m0 + row) * D_ + k0 + gch * 8);
      async16(&WsA[row][lch * 8], Wa + (size_t)(n0 + row) * D_ + k0 + gch * 8);
      if (NZ == 2)
        async16(&WsB[row][lch * 8], Wb + (size_t)(n0 + row) * D_ + k0 + gch * 8);
    }
    __syncthreads();
#pragma unroll
    for (int s = 0; s < 2; ++s) {
      const int rB = w * 16 + c;
      const short8 bt = *(const short8*)&Xs[rB][(((s * 4 + quad) ^ (rB & 7)) & 7) * 8];
#pragma unroll
      for (int i = 0; i < 4; ++i) {
        const int rA = i * 16 + c;
        const int col = (((s * 4 + quad) ^ (rA & 7)) & 7) * 8;
        acc[0][i] = MFMA16(*(const short8*)&WsA[rA][col], bt, acc[0][i]);
        if (NZ == 2) acc[1][i] = MFMA16(*(const short8*)&WsB[rA][col], bt, acc[1][i]);
      }
    }
  }
  const int token = m0 + w * 16 + c;
#pragma unroll
  for (int i = 0; i < 4; ++i) {
    const size_t off = (size_t)token * D_ + n0 + i * 16 + quad * 4;
    if (F32OUT) {
      float4 v;
      v.x = acc[0][i][0]; v.y = acc[0][i][1]; v.z = acc[0][i][2]; v.w = acc[0][i][3];
      *(float4*)((float*)Ca + off) = v;
    } else {
      ushort4 va;
      va.x = f2bf(acc[0][i][0] * sA); va.y = f2bf(acc[0][i][1] * sA);
      va.z = f2bf(acc[0][i][2] * sA); va.w = f2bf(acc[0][i][3] * sA);
      *(ushort4*)((ushort*)Ca + off) = va;
      if (NZ == 2) {
        ushort4 vb;
        vb.x = f2bf(acc[1][i][0]); vb.y = f2bf(acc[1][i][1]);
        vb.z = f2bf(acc[1][i][2]); vb.w = f2bf(acc[1][i][3]);
        *(ushort4*)((ushort*)Cb + off) = vb;
      }
    }
  }
}

// ---- fully fused MHA, grid-size-agnostic (JPB = jobs per block) ----
template <int JPB, int MW>
__global__ __launch_bounds__(256, MW) void fused_mha(
    const float* __restrict__ queries, const int* __restrict__ mask,
    const float* __restrict__ Wq, const float* __restrict__ Wk,
    const float* __restrict__ Wc, float* __restrict__ out,
    ushort* __restrict__ Xb, ushort* __restrict__ Wqb, ushort* __restrict__ Wkb,
    ushort* __restrict__ Wcb, ushort* __restrict__ Qb, ushort* __restrict__ Kb,
    ushort* __restrict__ Ab, uint32_t* __restrict__ pk) {
  __shared__ __align__(16) char smem[33792];
  const int t = threadIdx.x;
  const int bx = blockIdx.x;
  const int nblk = 1024 / JPB;  // grid size
  cg::grid_group grid = cg::this_grid();

  // ======== stage 0: mask pack + fp32->bf16 conversions ========
  {
    const int nth = nblk << 8, nwv = nblk << 2;
    const int tid = (bx << 8) + t;
    const int lane = t & 63;
    const int wid = tid >> 6;
    for (int i = wid; i < 65536; i += nwv) {         // 256-key chunks
      const int4 m = ((const int4*)mask)[(size_t)i * 64 + lane];
      uint32_t nib = (uint32_t)(m.x != 0) | ((uint32_t)(m.y != 0) << 1) |
                     ((uint32_t)(m.z != 0) << 2) | ((uint32_t)(m.w != 0) << 3);
      nib |= __shfl_xor(nib, 1) << 4;
      nib |= __shfl_xor(nib, 2) << 8;
      nib |= __shfl_xor(nib, 4) << 16;
      if ((lane & 7) == 0) pk[i * 8 + (lane >> 3)] = nib;
    }
    for (int j = tid; j < 1048576; j += nth) {       // queries: 1M float4
      const float4 v = ((const float4*)queries)[j];
      ushort4 o; o.x = f2bf(v.x); o.y = f2bf(v.y); o.z = f2bf(v.z); o.w = f2bf(v.w);
      ((ushort4*)Xb)[j] = o;
    }
    for (int j = tid; j < 196608; j += nth) {        // Wq|Wk|Wc: 192K float4
      const int wi = j >> 16, off = j & 65535;
      const float* src = (wi == 0) ? Wq : (wi == 1) ? Wk : Wc;
      const float4 v = ((const float4*)src)[off];
      ushort4 o; o.x = f2bf(v.x); o.y = f2bf(v.y); o.z = f2bf(v.z); o.w = f2bf(v.w);
      ((ushort4*)Wqb)[j] = o;
    }
  }
  grid.sync();

  // ======== stage 1: Q = X@Wq^T (scaled), K = X@Wk^T — 1024 tile jobs ========
  for (int job = bx; job < 1024; job += nblk)
    gemm64<2, 0>(Xb, Wqb, Wkb, Qb, Kb, NORM2_, job >> 3, job & 7, smem, t);
  grid.sync();

  // ======== stage 2: flash attention (V == K), no online max ========
  for (int job = bx; job < 1024; job += nblk) {
    const int b = job >> 8, h = (job >> 5) & 7, qt = job & 31;
    const int q0 = qt * 64;
    const int w = t >> 6, lane = t & 63, quad = lane >> 4, c = lane & 15;
    ushort(*Qs)[64] = (ushort(*)[64])smem;                    // 8K
    ushort(*Ks)[64] = (ushort(*)[64])(smem + 8192);           // 8K
    uint32_t(*KtU)[32] = (uint32_t(*)[32])(smem + 16384);     // 8K
    ushort(*Pq)[16][72] = (ushort(*)[16][72])(smem + 24576);  // 9K

    __syncthreads();  // prior job's LDS reads done before Q restage
#pragma unroll
    for (int p = 0; p < 2; ++p) {
      const int id = t + p * 256;
      const int row = id >> 3, lch = id & 7, gch = lch ^ (row & 7);
      async16(&Qs[row][lch * 8], Qb + (size_t)(b * N_ + q0 + row) * D_ + h * 64 + gch * 8);
    }
    __syncthreads();
    const int rq = (w << 4) + c;
    const short8 bq0 = *(const short8*)&Qs[rq][((quad ^ (rq & 7)) & 7) * 8];
    const short8 bq1 = *(const short8*)&Qs[rq][(((4 + quad) ^ (rq & 7)) & 7) * 8];

    short8 vones;
#pragma unroll
    for (int i = 0; i < 8; ++i) vones[i] = (short)0x3F80;  // bf16 1.0 splat

    f32x4 o[4];
#pragma unroll
    for (int i = 0; i < 4; ++i) o[i] = (f32x4){0.f, 0.f, 0.f, 0.f};
    f32x4 o5 = (f32x4){0.f, 0.f, 0.f, 0.f};  // l via ones-MFMA

    const int kp = t >> 3, ch = t & 7;  // staging: key-pair, d-chunk
    const ushort* kb0 = Kb + (size_t)(b * N_ + 2 * kp) * D_ + h * 64 + ch * 8;
    const uint32_t* pkq = pk + ((size_t)(b * N_ + q0 + (w << 4) + c) << 6);

    uint4 c0 = *(const uint4*)kb0;
    uint4 c1 = *(const uint4*)(kb0 + D_);
    uint2 cm = *(const uint2*)pkq;
    uint4 nx0, nx1; uint2 nxm;

    const int NT = N_ / 64;
    for (int kt = 0; kt < NT; ++kt) {
      __syncthreads();  // prior tile's frag reads done
      const int r0 = 2 * kp, r1 = r0 + 1;
      *(uint4*)&Ks[r0][((ch ^ (r0 & 7)) & 7) * 8] = c0;
      *(uint4*)&Ks[r1][((ch ^ (r1 & 7)) & 7) * 8] = c1;
      const uint32_t* a0 = (const uint32_t*)&c0;
      const uint32_t* a1 = (const uint32_t*)&c1;
#pragma unroll
      for (int m = 0; m < 4; ++m) {
        const uint32_t lo = __builtin_amdgcn_perm(a1[m], a0[m], 0x05040100);
        const uint32_t hi = __builtin_amdgcn_perm(a1[m], a0[m], 0x07060302);
        const int j0 = 2 * m, j1 = 2 * m + 1;
        KtU[ch * 8 + j0][(kp & 3) | ((((kp >> 2) ^ j0 ^ ch) & 7) << 2)] = lo;
        KtU[ch * 8 + j1][(kp & 3) | ((((kp >> 2) ^ j1 ^ ch) & 7) << 2)] = hi;
      }
      __syncthreads();

      if (kt + 1 < NT) {
        const ushort* kbn = kb0 + (size_t)(kt + 1) * 64 * D_;
        nx0 = *(const uint4*)kbn;
        nx1 = *(const uint4*)(kbn + D_);
        nxm = *(const uint2*)(pkq + (kt + 1) * 2);
      }

#pragma unroll
      for (int tI = 0; tI < 4; ++tI) {
        const int rk = tI * 16 + c;
        const short8 aK0 = *(const short8*)&Ks[rk][((quad ^ (rk & 7)) & 7) * 8];
        const short8 aK1 = *(const short8*)&Ks[rk][(((4 + quad) ^ (rk & 7)) & 7) * 8];
        f32x4 z = (f32x4){0.f, 0.f, 0.f, 0.f};
        z = MFMA16(aK0, bq0, z);
        z = MFMA16(aK1, bq1, z);
        const uint32_t mw = (tI < 2) ? cm.x : cm.y;
        const int bb = ((tI & 1) << 4) + quad * 4;
        uint32_t pb[4];
#pragma unroll
        for (int r = 0; r < 4; ++r) {
          const float sv = ((mw >> (bb + r)) & 1u) ? -INFINITY : z[r];
          pb[r] = __float_as_uint(EXP2(sv));  // exp2(-inf) = 0
        }
        const uint32_t pw0 = __builtin_amdgcn_perm(pb[1], pb[0], 0x07060302);
        const uint32_t pw1 = __builtin_amdgcn_perm(pb[3], pb[2], 0x07060302);
        *(uint2*)&Pq[w][c][tI * 16 + quad * 4] = make_uint2(pw0, pw1);
      }

      const short8 bp0 = *(const short8*)&Pq[w][c][quad * 8];
      const short8 bp1 = *(const short8*)&Pq[w][c][32 + quad * 8];
      o5 = MFMA16(vones, bp0, o5);
      o5 = MFMA16(vones, bp1, o5);
#pragma unroll
      for (int dt = 0; dt < 4; ++dt) {
        const int dd = dt * 16 + c;
        const int g = (c & 7) ^ ((2 * dt + (c >> 3)) & 7);
        const short8 aV0 = *(const short8*)&KtU[dd][((quad ^ g) & 7) << 2];
        const short8 aV1 = *(const short8*)&KtU[dd][(((4 + quad) ^ g) & 7) << 2];
        o[dt] = MFMA16(aV0, bp0, o[dt]);
        o[dt] = MFMA16(aV1, bp1, o[dt]);
      }

      if (kt + 1 < NT) { c0 = nx0; c1 = nx1; cm = nxm; }
    }

    const float inv = 1.f / o5[0];
#pragma unroll
    for (int dt = 0; dt < 4; ++dt) {
      ushort4 v; v.x = f2bf(o[dt][0] * inv); v.y = f2bf(o[dt][1] * inv);
      v.z = f2bf(o[dt][2] * inv); v.w = f2bf(o[dt][3] * inv);
      *(ushort4*)(Ab + (size_t)(b * N_ + q0 + (w << 4) + c) * D_ + h * 64 +
                  dt * 16 + quad * 4) = v;
    }
  }
  grid.sync();

  // ======== stage 3: out = A@Wc^T (f32) — 1024 tile jobs ========
  for (int job = bx; job < 1024; job += nblk)
    gemm64<1, 1>(Ab, Wcb, nullptr, out, nullptr, 1.0f, job >> 3, job & 7, smem, t);
}

// ================= round-5 fallback kernels (verified path) =================
__global__ __launch_bounds__(256) void prep(const float* __restrict__ q,
                                            const int* __restrict__ mask,
                                            const float* __restrict__ wq,
                                            const float* __restrict__ wk,
                                            const float* __restrict__ wc,
                                            ushort* __restrict__ Xb,
                                            ushort* __restrict__ Wb,
                                            uint32_t* __restrict__ pk) {
  const int bx = blockIdx.x;
  if (bx < 2048) {
    const int lane = threadIdx.x & 63;
    const int wid = ((bx << 8) + threadIdx.x) >> 6;
    for (int i = wid; i < 65536; i += 8192) {
      const int4 m = ((const int4*)mask)[(size_t)i * 64 + lane];
      uint32_t nib = (uint32_t)(m.x != 0) | ((uint32_t)(m.y != 0) << 1) |
                     ((uint32_t)(m.z != 0) << 2) | ((uint32_t)(m.w != 0) << 3);
      nib |= __shfl_xor(nib, 1) << 4;
      nib |= __shfl_xor(nib, 2) << 8;
      nib |= __shfl_xor(nib, 4) << 16;
      if ((lane & 7) == 0) pk[i * 8 + (lane >> 3)] = nib;
    }
  } else if (bx < 3072) {
    const int i = ((bx - 2048) << 8) + threadIdx.x;
    for (int j = i; j < 1048576; j += 262144) {
      const float4 v = ((const float4*)q)[j];
      ushort4 o; o.x = f2bf(v.x); o.y = f2bf(v.y); o.z = f2bf(v.z); o.w = f2bf(v.w);
      ((ushort4*)Xb)[j] = o;
    }
  } else {
    const int i = ((bx - 3072) << 8) + threadIdx.x;
    for (int j = i; j < 196608; j += 24576) {
      const int wi = j >> 16, off = j & 65535;
      const float* src = (wi == 0) ? wq : (wi == 1) ? wk : wc;
      const float4 v = ((const float4*)src)[off];
      ushort4 o; o.x = f2bf(v.x); o.y = f2bf(v.y); o.z = f2bf(v.z); o.w = f2bf(v.w);
      ((ushort4*)Wb)[j] = o;
    }
  }
}

template <int F32OUT>
__global__ __launch_bounds__(256) void gemm128(const ushort* __restrict__ X,
                                               const ushort* __restrict__ W0,
                                               const ushort* __restrict__ W1,
                                               void* __restrict__ C0,
                                               void* __restrict__ C1,
                                               float s0, float s1) {
  const ushort* Wp = (blockIdx.z == 0) ? W0 : W1;
  void* Cp = (blockIdx.z == 0) ? C0 : C1;
  const float sc = (blockIdx.z == 0) ? s0 : s1;
  const int t = threadIdx.x;
  const int w = t >> 6, lane = t & 63, quad = lane >> 4, c = lane & 15;
  const int wm = w & 1, wn = w >> 1;
  const int n0 = blockIdx.x * 128, m0 = blockIdx.y * 128;
  __shared__ __align__(16) ushort Xs[128][64];
  __shared__ __align__(16) ushort Ws[128][64];
  f32x4 acc[4][4];
#pragma unroll
  for (int i = 0; i < 4; ++i)
#pragma unroll
    for (int j = 0; j < 4; ++j) acc[i][j] = (f32x4){0.f, 0.f, 0.f, 0.f};

  for (int k0 = 0; k0 < D_; k0 += 64) {
    __syncthreads();
#pragma unroll
    for (int g = 0; g < 4; ++g) {
      const int id = w * 256 + g * 64 + lane;
      const int row = id >> 3, lch = id & 7;
      const int gch = lch ^ (row & 7);
      async16(&Xs[row][lch * 8], X + (size_t)(m0 + row) * D_ + k0 + gch * 8);
      async16(&Ws[row][lch * 8], Wp + (size_t)(n0 + row) * D_ + k0 + gch * 8);
    }
    __syncthreads();
#pragma unroll
    for (int s = 0; s < 2; ++s) {
      short8 af[4], bt[4];
#pragma unroll
      for (int i = 0; i < 4; ++i) {
        const int rA = wn * 64 + i * 16 + c;
        af[i] = *(const short8*)&Ws[rA][(((s * 4 + quad) ^ (rA & 7)) & 7) * 8];
        const int rB = wm * 64 + i * 16 + c;
        bt[i] = *(const short8*)&Xs[rB][(((s * 4 + quad) ^ (rB & 7)) & 7) * 8];
      }
#pragma unroll
      for (int i = 0; i < 4; ++i)
#pragma unroll
        for (int j = 0; j < 4; ++j) acc[i][j] = MFMA16(af[i], bt[j], acc[i][j]);
    }
  }
#pragma unroll
  for (int i = 0; i < 4; ++i)
#pragma unroll
    for (int j = 0; j < 4; ++j) {
      const size_t off =
          (size_t)(m0 + wm * 64 + j * 16 + c) * D_ + n0 + wn * 64 + i * 16 + quad * 4;
      if (F32OUT) {
        float4 v; v.x = acc[i][j][0]; v.y = acc[i][j][1]; v.z = acc[i][j][2]; v.w = acc[i][j][3];
        *(float4*)((float*)Cp + off) = v;
      } else {
        ushort4 v; v.x = f2bf(acc[i][j][0] * sc); v.y = f2bf(acc[i][j][1] * sc);
        v.z = f2bf(acc[i][j][2] * sc); v.w = f2bf(acc[i][j][3] * sc);
        *(ushort4*)((ushort*)Cp + off) = v;
      }
    }
}

__global__ __launch_bounds__(256) void attn_mfma(const ushort* __restrict__ Qb,
                                                 const ushort* __restrict__ Kb,
                                                 const uint32_t* __restrict__ pk,
                                                 ushort* __restrict__ Ab) {
  const int qt = blockIdx.x, h = blockIdx.y, b = blockIdx.z;
  const int q0 = qt * 64;
  const int t = threadIdx.x;
  const int w = t >> 6, lane = t & 63, quad = lane >> 4, c = lane & 15;

  __shared__ __align__(16) ushort Qs[64][64];
  __shared__ __align__(16) ushort Ks[64][64];
  __shared__ __align__(16) uint32_t KtU[64][32];
  __shared__ __align__(16) ushort Pq[4][16][72];

#pragma unroll
  for (int p = 0; p < 2; ++p) {
    const int id = t + p * 256;
    const int row = id >> 3, lch = id & 7, gch = lch ^ (row & 7);
    async16(&Qs[row][lch * 8], Qb + (size_t)(b * N_ + q0 + row) * D_ + h * 64 + gch * 8);
  }
  __syncthreads();
  const int rq = (w << 4) + c;
  const short8 bq0 = *(const short8*)&Qs[rq][((quad ^ (rq & 7)) & 7) * 8];
  const short8 bq1 = *(const short8*)&Qs[rq][(((4 + quad) ^ (rq & 7)) & 7) * 8];

  float lacc = 0.f;
  f32x4 o[4];
#pragma unroll
  for (int i = 0; i < 4; ++i) o[i] = (f32x4){0.f, 0.f, 0.f, 0.f};

  const int kp = t >> 3, ch = t & 7;
  const ushort* kb0 = Kb + (size_t)(b * N_ + 2 * kp) * D_ + h * 64 + ch * 8;
  const uint32_t* pkq = pk + ((size_t)(b * N_ + q0 + (w << 4) + c) << 6);

  uint4 c0 = *(const uint4*)kb0;
  uint4 c1 = *(const uint4*)(kb0 + D_);
  uint2 cm = *(const uint2*)pkq;
  uint4 nx0, nx1; uint2 nxm;

  const int NT = N_ / 64;
  for (int kt = 0; kt < NT; ++kt) {
    __syncthreads();
    const int r0 = 2 * kp, r1 = r0 + 1;
    *(uint4*)&Ks[r0][((ch ^ (r0 & 7)) & 7) * 8] = c0;
    *(uint4*)&Ks[r1][((ch ^ (r1 & 7)) & 7) * 8] = c1;
    const uint32_t* a0 = (const uint32_t*)&c0;
    const uint32_t* a1 = (const uint32_t*)&c1;
#pragma unroll
    for (int m = 0; m < 4; ++m) {
      const uint32_t lo = __builtin_amdgcn_perm(a1[m], a0[m], 0x05040100);
      const uint32_t hi = __builtin_amdgcn_perm(a1[m], a0[m], 0x07060302);
      const int j0 = 2 * m, j1 = 2 * m + 1;
      KtU[ch * 8 + j0][(kp & 3) | ((((kp >> 2) ^ j0 ^ ch) & 7) << 2)] = lo;
      KtU[ch * 8 + j1][(kp & 3) | ((((kp >> 2) ^ j1 ^ ch) & 7) << 2)] = hi;
    }
    __syncthreads();

    if (kt + 1 < NT) {
      const ushort* kbn = kb0 + (size_t)(kt + 1) * 64 * D_;
      nx0 = *(const uint4*)kbn;
      nx1 = *(const uint4*)(kbn + D_);
      nxm = *(const uint2*)(pkq + (kt + 1) * 2);
    }

#pragma unroll
    for (int tI = 0; tI < 4; ++tI) {
      const int rk = tI * 16 + c;
      const short8 aK0 = *(const short8*)&Ks[rk][((quad ^ (rk & 7)) & 7) * 8];
      const short8 aK1 = *(const short8*)&Ks[rk][(((4 + quad) ^ (rk & 7)) & 7) * 8];
      f32x4 z = (f32x4){0.f, 0.f, 0.f, 0.f};
      z = MFMA16(aK0, bq0, z);
      z = MFMA16(aK1, bq1, z);
      const uint32_t mw = (tI < 2) ? cm.x : cm.y;
      const int bb = ((tI & 1) << 4) + quad * 4;
      float p[4];
#pragma unroll
      for (int r = 0; r < 4; ++r) {
        const float sv = ((mw >> (bb + r)) & 1u) ? -INFINITY : z[r];
        p[r] = EXP2(sv);
        lacc += p[r];
      }
      const uint32_t pw0 =
          __builtin_amdgcn_perm(__float_as_uint(p[1]), __float_as_uint(p[0]), 0x07060302);
      const uint32_t pw1 =
          __builtin_amdgcn_perm(__float_as_uint(p[3]), __float_as_uint(p[2]), 0x07060302);
      *(uint2*)&Pq[w][c][tI * 16 + quad * 4] = make_uint2(pw0, pw1);
    }

    const short8 bp0 = *(const short8*)&Pq[w][c][quad * 8];
    const short8 bp1 = *(const short8*)&Pq[w][c][32 + quad * 8];
#pragma unroll
    for (int dt = 0; dt < 4; ++dt) {
      const int dd = dt * 16 + c;
      const int g = (c & 7) ^ ((2 * dt + (c >> 3)) & 7);
      const short8 aV0 = *(const short8*)&KtU[dd][((quad ^ g) & 7) << 2];
      const short8 aV1 = *(const short8*)&KtU[dd][(((4 + quad) ^ g) & 7) << 2];
      o[dt] = MFMA16(aV0, bp0, o[dt]);
      o[dt] = MFMA16(aV1, bp1, o[dt]);
    }

    if (kt + 1 < NT) { c0 = nx0; c1 = nx1; cm = nxm; }
  }

  float l = lacc;
  l += __shfl_xor(l, 16);
  l += __shfl_xor(l, 32);
  const float inv = 1.f / l;
#pragma unroll
  for (int dt = 0; dt < 4; ++dt) {
    ushort4 v; v.x = f2bf(o[dt][0] * inv); v.y = f2bf(o[dt][1] * inv);
    v.z = f2bf(o[dt][2] * inv); v.w = f2bf(o[dt][3] * inv);
    *(ushort4*)(Ab + (size_t)(b * N_ + q0 + (w << 4) + c) * D_ + h * 64 + dt * 16 + quad * 4) = v;
  }
}

extern "C" void kernel_launch(void* const* d_in, const int* in_sizes, int n_in,
                              void* d_out, int out_size, void* d_ws, size_t ws_size,
                              hipStream_t stream) {
  const float* queries = (const float*)d_in[0];
  const int* mask = (const int*)d_in[1];
  const float* Wq = (const float*)d_in[2];
  const float* Wk = (const float*)d_in[3];
  const float* Wc = (const float*)d_in[4];
  float* out = (float*)d_out;

  const size_t nTok = (size_t)B_ * N_;
  const size_t nXD = nTok * D_;
  const size_t nW = (size_t)D_ * D_;
  ushort* Xb = (ushort*)d_ws;
  ushort* Wqb = Xb + nXD;     // Wq|Wk|Wc contiguous
  ushort* Wkb = Wqb + nW;
  ushort* Wcb = Wkb + nW;
  ushort* Qb = Wcb + nW;
  ushort* Kb = Qb + nXD;
  ushort* Ab = Kb + nXD;
  uint32_t* pk = (uint32_t*)(Ab + nXD);

  void* args[] = {(void*)&queries, (void*)&mask, (void*)&Wq, (void*)&Wk,
                  (void*)&Wc,      (void*)&out,  (void*)&Xb, (void*)&Wqb,
                  (void*)&Wkb,     (void*)&Wcb,  (void*)&Qb, (void*)&Kb,
                  (void*)&Ab,      (void*)&pk};

  hipError_t e = hipLaunchCooperativeKernel(
      reinterpret_cast<void*>(&fused_mha<1, 4>), dim3(1024), dim3(256), args, 0, stream);
  if (e != hipSuccess) {
    (void)hipGetLastError();
    e = hipLaunchCooperativeKernel(
        reinterpret_cast<void*>(&fused_mha<2, 2>), dim3(512), dim3(256), args, 0, stream);
  }
  if (e != hipSuccess) {
    (void)hipGetLastError();
    // verified round-5 path
    prep<<<3168, 256, 0, stream>>>(queries, mask, Wq, Wk, Wc, Xb, Wqb, pk);
    gemm128<0><<<dim3(D_ / 128, (int)(nTok / 128), 2), 256, 0, stream>>>(
        Xb, Wqb, Wkb, Qb, Kb, NORM2_, 1.0f);
    attn_mfma<<<dim3(N_ / 64, H_, B_), 256, 0, stream>>>(Qb, Kb, pk, Ab);
    gemm128<1><<<dim3(D_ / 128, (int)(nTok / 128), 1), 256, 0, stream>>>(
        Ab, Wcb, nullptr, out, nullptr, 1.0f, 1.0f);
  }
}

// Round 8
// 226.030 us; speedup vs baseline: 2.4610x; 2.4610x over previous
//
#include <hip/hip_runtime.h>
#include <hip/hip_bf16.h>
#include <math.h>

#define B_ 4
#define N_ 2048
#define D_ 512
#define H_ 8
// NORM * log2(e): scores pre-scaled so softmax uses exp2 directly.
#define NORM2_ 0.18033688011112042f

typedef __attribute__((ext_vector_type(8))) short short8;   // 8 bf16 (4 VGPRs)
typedef __attribute__((ext_vector_type(4))) float f32x4;    // MFMA C/D
#define MFMA16(a, b, c) __builtin_amdgcn_mfma_f32_16x16x32_bf16(a, b, c, 0, 0, 0)
#define EXP2(x) __builtin_amdgcn_exp2f(x)

// pack two f32 -> two bf16 (RNE, native v_cvt_pk_bf16_f32); .x at low half
static __device__ __forceinline__ uint32_t pk2(float lo, float hi) {
  __hip_bfloat162 h = __float22bfloat162_rn(make_float2(lo, hi));
  return *(reinterpret_cast<uint32_t*>(&h));
}

// async global->LDS, 16B per lane. LDS dest must be wave-uniform base + lane*16.
static __device__ __forceinline__ void async16(const ushort* lds, const ushort* g) {
  __builtin_amdgcn_global_load_lds(
      (const __attribute__((address_space(1))) uint32_t*)g,
      (__attribute__((address_space(3))) uint32_t*)(ushort*)lds, 16, 0, 0);
}

// ---------------- launch 1: QK projection (inline fp32->bf16) + mask pack ----------------
// blocks [0,512): 128x128 gemm tiles; bx>>8 picks (Wq->Qb, scaled) / (Wk->Kb).
// blocks [512,1024): mask int32 -> bitmask.
__global__ __launch_bounds__(256) void gemmqk_pack(const float* __restrict__ X,
                                                   const float* __restrict__ Wq,
                                                   const float* __restrict__ Wk,
                                                   const int* __restrict__ mask,
                                                   ushort* __restrict__ Qb,
                                                   ushort* __restrict__ Kb,
                                                   uint32_t* __restrict__ pk) {
  __shared__ __align__(16) ushort Xs[128][64];
  __shared__ __align__(16) ushort Ws[128][64];
  const int bx = blockIdx.x;
  const int t = threadIdx.x;

  if (bx >= 512) {
    // ---- mask pack: 4 keys/lane via int4, shuffle-OR nibble assembly ----
    const int lane = t & 63;
    const int wid = (((bx - 512) << 8) + t) >> 6;    // 2048 waves
    for (int i = wid; i < 65536; i += 2048) {        // 256-key chunks
      const int4 m = ((const int4*)mask)[(size_t)i * 64 + lane];
      uint32_t nib = (uint32_t)(m.x != 0) | ((uint32_t)(m.y != 0) << 1) |
                     ((uint32_t)(m.z != 0) << 2) | ((uint32_t)(m.w != 0) << 3);
      nib |= __shfl_xor(nib, 1) << 4;
      nib |= __shfl_xor(nib, 2) << 8;
      nib |= __shfl_xor(nib, 4) << 16;
      if ((lane & 7) == 0) pk[i * 8 + (lane >> 3)] = nib;
    }
    return;
  }

  const float* Wp = (bx >> 8) ? Wk : Wq;
  ushort* Cp = (bx >> 8) ? Kb : Qb;
  const float sc = (bx >> 8) ? 1.0f : NORM2_;
  const int tile = bx & 255;
  const int n0 = (tile & 3) * 128, m0 = (tile >> 2) * 128;
  const int w = t >> 6, lane = t & 63, quad = lane >> 4, c = lane & 15;
  const int wm = w & 1, wn = w >> 1;

  f32x4 acc[4][4];
#pragma unroll
  for (int i = 0; i < 4; ++i)
#pragma unroll
    for (int j = 0; j < 4; ++j) acc[i][j] = (f32x4){0.f, 0.f, 0.f, 0.f};

  for (int k0 = 0; k0 < D_; k0 += 64) {
    __syncthreads();
    // manual staging with inline cvt; swizzle on the global side (gch = lch ^ row&7)
#pragma unroll
    for (int g = 0; g < 4; ++g) {
      const int id = w * 256 + g * 64 + lane;        // 1024 ids: 128 rows x 8 chunks
      const int row = id >> 3, lch = id & 7, gch = lch ^ (row & 7);
      const float* xs = X + (size_t)(m0 + row) * D_ + k0 + gch * 8;
      const float4 xa = *(const float4*)xs;
      const float4 xb = *(const float4*)(xs + 4);
      uint4 u;
      u.x = pk2(xa.x, xa.y); u.y = pk2(xa.z, xa.w);
      u.z = pk2(xb.x, xb.y); u.w = pk2(xb.z, xb.w);
      *(uint4*)&Xs[row][lch * 8] = u;
      const float* ws = Wp + (size_t)(n0 + row) * D_ + k0 + gch * 8;
      const float4 wa = *(const float4*)ws;
      const float4 wb = *(const float4*)(ws + 4);
      uint4 v;
      v.x = pk2(wa.x, wa.y); v.y = pk2(wa.z, wa.w);
      v.z = pk2(wb.x, wb.y); v.w = pk2(wb.z, wb.w);
      *(uint4*)&Ws[row][lch * 8] = v;
    }
    __syncthreads();
#pragma unroll
    for (int s = 0; s < 2; ++s) {
      short8 af[4], bt[4];
#pragma unroll
      for (int i = 0; i < 4; ++i) {
        const int rA = wn * 64 + i * 16 + c;
        af[i] = *(const short8*)&Ws[rA][(((s * 4 + quad) ^ (rA & 7)) & 7) * 8];
        const int rB = wm * 64 + i * 16 + c;
        bt[i] = *(const short8*)&Xs[rB][(((s * 4 + quad) ^ (rB & 7)) & 7) * 8];
      }
#pragma unroll
      for (int i = 0; i < 4; ++i)
#pragma unroll
        for (int j = 0; j < 4; ++j) acc[i][j] = MFMA16(af[i], bt[j], acc[i][j]);
    }
  }
  // D[m=feature][n=token] (C^T per tile), bf16 out
#pragma unroll
  for (int i = 0; i < 4; ++i)
#pragma unroll
    for (int j = 0; j < 4; ++j) {
      const size_t off =
          (size_t)(m0 + wm * 64 + j * 16 + c) * D_ + n0 + wn * 64 + i * 16 + quad * 4;
      uint2 uv;
      uv.x = pk2(acc[i][j][0] * sc, acc[i][j][1] * sc);
      uv.y = pk2(acc[i][j][2] * sc, acc[i][j][3] * sc);
      *(uint2*)(Cp + off) = uv;
    }
}

// ---------------- launch 2: flash attention, bf16 MFMA, V == K, no online max ----------------
// Scores in log2 domain (Q pre-scaled by NORM*log2e), |s| small -> no overflow:
//   p = exp2(masked ? -inf : s); O += p*V; l += p;  epilogue O/l.
// Qs aliases Pq (Q frags live in registers after the one-time read) -> LDS 25.8 KB.
__global__ __launch_bounds__(256) void attn_mfma(const ushort* __restrict__ Qb,
                                                 const ushort* __restrict__ Kb,
                                                 const uint32_t* __restrict__ pk,
                                                 ushort* __restrict__ Ab) {
  const int qt = blockIdx.x, h = blockIdx.y, b = blockIdx.z;
  const int q0 = qt * 64;
  const int t = threadIdx.x;
  const int w = t >> 6, lane = t & 63, quad = lane >> 4, c = lane & 15;

  __shared__ __align__(16) ushort Ks[64][64];        // 8K: K rows, swizzled chunks
  __shared__ __align__(16) uint32_t KtU[64][32];     // 8K: V^T key-pair u32, swizzled
  __shared__ __align__(16) ushort QP[4][16][72];     // 9.2K: Qs (staging) then Pq
  ushort(*Qs)[64] = (ushort(*)[64]) & QP[0][0][0];
  ushort(*Pq)[16][72] = QP;

#pragma unroll
  for (int p = 0; p < 2; ++p) {
    const int id = t + p * 256;
    const int row = id >> 3, lch = id & 7, gch = lch ^ (row & 7);
    async16(&Qs[row][lch * 8], Qb + (size_t)(b * N_ + q0 + row) * D_ + h * 64 + gch * 8);
  }
  __syncthreads();
  const int rq = (w << 4) + c;
  const short8 bq0 = *(const short8*)&Qs[rq][((quad ^ (rq & 7)) & 7) * 8];
  const short8 bq1 = *(const short8*)&Qs[rq][(((4 + quad) ^ (rq & 7)) & 7) * 8];

  float lacc = 0.f;
  f32x4 o[4];
#pragma unroll
  for (int i = 0; i < 4; ++i) o[i] = (f32x4){0.f, 0.f, 0.f, 0.f};

  const int kp = t >> 3, ch = t & 7;  // staging: key-pair, d-chunk
  const ushort* kb0 = Kb + (size_t)(b * N_ + 2 * kp) * D_ + h * 64 + ch * 8;
  const uint32_t* pkq = pk + ((size_t)(b * N_ + q0 + (w << 4) + c) << 6);

  uint4 c0 = *(const uint4*)kb0;
  uint4 c1 = *(const uint4*)(kb0 + D_);
  uint2 cm = *(const uint2*)pkq;
  uint4 nx0, nx1; uint2 nxm;

  const int NT = N_ / 64;
  for (int kt = 0; kt < NT; ++kt) {
    __syncthreads();  // prior tile's frag reads (and initial Qs reads) done
    const int r0 = 2 * kp, r1 = r0 + 1;
    *(uint4*)&Ks[r0][((ch ^ (r0 & 7)) & 7) * 8] = c0;
    *(uint4*)&Ks[r1][((ch ^ (r1 & 7)) & 7) * 8] = c1;
    const uint32_t* a0 = (const uint32_t*)&c0;
    const uint32_t* a1 = (const uint32_t*)&c1;
#pragma unroll
    for (int m = 0; m < 4; ++m) {
      const uint32_t lo = __builtin_amdgcn_perm(a1[m], a0[m], 0x05040100);  // even d
      const uint32_t hi = __builtin_amdgcn_perm(a1[m], a0[m], 0x07060302);  // odd d
      const int j0 = 2 * m, j1 = 2 * m + 1;
      KtU[ch * 8 + j0][(kp & 3) | ((((kp >> 2) ^ j0 ^ ch) & 7) << 2)] = lo;
      KtU[ch * 8 + j1][(kp & 3) | ((((kp >> 2) ^ j1 ^ ch) & 7) << 2)] = hi;
    }
    __syncthreads();

    if (kt + 1 < NT) {  // prefetch next tile while computing
      const ushort* kbn = kb0 + (size_t)(kt + 1) * 64 * D_;
      nx0 = *(const uint4*)kbn;
      nx1 = *(const uint4*)(kbn + D_);
      nxm = *(const uint2*)(pkq + (kt + 1) * 2);
    }

    // S^T = K·Q^T, p = exp2(masked ? -inf : s)
#pragma unroll
    for (int tI = 0; tI < 4; ++tI) {
      const int rk = tI * 16 + c;
      const short8 aK0 = *(const short8*)&Ks[rk][((quad ^ (rk & 7)) & 7) * 8];
      const short8 aK1 = *(const short8*)&Ks[rk][(((4 + quad) ^ (rk & 7)) & 7) * 8];
      f32x4 z = (f32x4){0.f, 0.f, 0.f, 0.f};
      z = MFMA16(aK0, bq0, z);
      z = MFMA16(aK1, bq1, z);
      const uint32_t mw = (tI < 2) ? cm.x : cm.y;
      const int bb = ((tI & 1) << 4) + quad * 4;
      float p[4];
#pragma unroll
      for (int r = 0; r < 4; ++r) {
        const float sv = ((mw >> (bb + r)) & 1u) ? -INFINITY : z[r];
        p[r] = EXP2(sv);  // exp2(-inf) = 0
        lacc += p[r];
      }
      const uint32_t pw0 =
          __builtin_amdgcn_perm(__float_as_uint(p[1]), __float_as_uint(p[0]), 0x07060302);
      const uint32_t pw1 =
          __builtin_amdgcn_perm(__float_as_uint(p[3]), __float_as_uint(p[2]), 0x07060302);
      *(uint2*)&Pq[w][c][tI * 16 + quad * 4] = make_uint2(pw0, pw1);
    }

    // O^T += V^T·P^T (unnormalized)
    const short8 bp0 = *(const short8*)&Pq[w][c][quad * 8];
    const short8 bp1 = *(const short8*)&Pq[w][c][32 + quad * 8];
#pragma unroll
    for (int dt = 0; dt < 4; ++dt) {
      const int dd = dt * 16 + c;
      const int g = (c & 7) ^ ((2 * dt + (c >> 3)) & 7);
      const short8 aV0 = *(const short8*)&KtU[dd][((quad ^ g) & 7) << 2];
      const short8 aV1 = *(const short8*)&KtU[dd][(((4 + quad) ^ g) & 7) << 2];
      o[dt] = MFMA16(aV0, bp0, o[dt]);
      o[dt] = MFMA16(aV1, bp1, o[dt]);
    }

    if (kt + 1 < NT) { c0 = nx0; c1 = nx1; cm = nxm; }
  }

  // epilogue: reduce l across quad-lanes, O/l -> Ab (bf16)
  float l = lacc;
  l += __shfl_xor(l, 16);
  l += __shfl_xor(l, 32);
  const float inv = 1.f / l;
#pragma unroll
  for (int dt = 0; dt < 4; ++dt) {
    uint2 uv;
    uv.x = pk2(o[dt][0] * inv, o[dt][1] * inv);
    uv.y = pk2(o[dt][2] * inv, o[dt][3] * inv);
    *(uint2*)(Ab + (size_t)(b * N_ + q0 + (w << 4) + c) * D_ + h * 64 + dt * 16 + quad * 4) = uv;
  }
}

// ---------------- launch 3: out = A@Wc^T, A bf16 via async16, Wc inline cvt, f32 out ----------------
__global__ __launch_bounds__(256) void gemmout(const ushort* __restrict__ A,
                                               const float* __restrict__ Wc,
                                               float* __restrict__ out) {
  __shared__ __align__(16) ushort Xs[128][64];
  __shared__ __align__(16) ushort Ws[128][64];
  const int t = threadIdx.x;
  const int w = t >> 6, lane = t & 63, quad = lane >> 4, c = lane & 15;
  const int wm = w & 1, wn = w >> 1;
  const int n0 = blockIdx.x * 128, m0 = blockIdx.y * 128;
  f32x4 acc[4][4];
#pragma unroll
  for (int i = 0; i < 4; ++i)
#pragma unroll
    for (int j = 0; j < 4; ++j) acc[i][j] = (f32x4){0.f, 0.f, 0.f, 0.f};

  for (int k0 = 0; k0 < D_; k0 += 64) {
    __syncthreads();
#pragma unroll
    for (int g = 0; g < 4; ++g) {
      const int id = w * 256 + g * 64 + lane;
      const int row = id >> 3, lch = id & 7, gch = lch ^ (row & 7);
      async16(&Xs[row][lch * 8], A + (size_t)(m0 + row) * D_ + k0 + gch * 8);
      const float* ws = Wc + (size_t)(n0 + row) * D_ + k0 + gch * 8;
      const float4 wa = *(const float4*)ws;
      const float4 wb = *(const float4*)(ws + 4);
      uint4 v;
      v.x = pk2(wa.x, wa.y); v.y = pk2(wa.z, wa.w);
      v.z = pk2(wb.x, wb.y); v.w = pk2(wb.z, wb.w);
      *(uint4*)&Ws[row][lch * 8] = v;
    }
    __syncthreads();
#pragma unroll
    for (int s = 0; s < 2; ++s) {
      short8 af[4], bt[4];
#pragma unroll
      for (int i = 0; i < 4; ++i) {
        const int rA = wn * 64 + i * 16 + c;
        af[i] = *(const short8*)&Ws[rA][(((s * 4 + quad) ^ (rA & 7)) & 7) * 8];
        const int rB = wm * 64 + i * 16 + c;
        bt[i] = *(const short8*)&Xs[rB][(((s * 4 + quad) ^ (rB & 7)) & 7) * 8];
      }
#pragma unroll
      for (int i = 0; i < 4; ++i)
#pragma unroll
        for (int j = 0; j < 4; ++j) acc[i][j] = MFMA16(af[i], bt[j], acc[i][j]);
    }
  }
#pragma unroll
  for (int i = 0; i < 4; ++i)
#pragma unroll
    for (int j = 0; j < 4; ++j) {
      const size_t off =
          (size_t)(m0 + wm * 64 + j * 16 + c) * D_ + n0 + wn * 64 + i * 16 + quad * 4;
      float4 v;
      v.x = acc[i][j][0]; v.y = acc[i][j][1]; v.z = acc[i][j][2]; v.w = acc[i][j][3];
      *(float4*)(out + off) = v;
    }
}

extern "C" void kernel_launch(void* const* d_in, const int* in_sizes, int n_in,
                              void* d_out, int out_size, void* d_ws, size_t ws_size,
                              hipStream_t stream) {
  const float* queries = (const float*)d_in[0];
  const int* mask = (const int*)d_in[1];
  const float* Wq = (const float*)d_in[2];
  const float* Wk = (const float*)d_in[3];
  const float* Wc = (const float*)d_in[4];
  float* out = (float*)d_out;

  const size_t nXD = (size_t)B_ * N_ * D_;
  ushort* Qb = (ushort*)d_ws;
  ushort* Kb = Qb + nXD;
  ushort* Ab = Kb + nXD;
  uint32_t* pk = (uint32_t*)(Ab + nXD);

  gemmqk_pack<<<1024, 256, 0, stream>>>(queries, Wq, Wk, mask, Qb, Kb, pk);
  attn_mfma<<<dim3(N_ / 64, H_, B_), 256, 0, stream>>>(Qb, Kb, pk, Ab);
  gemmout<<<dim3(D_ / 128, (B_ * N_) / 128), 256, 0, stream>>>(Ab, Wc, out);
}

// Round 9
// 218.910 us; speedup vs baseline: 2.5410x; 1.0325x over previous
//
#include <hip/hip_runtime.h>
#include <hip/hip_bf16.h>
#include <math.h>

#define B_ 4
#define N_ 2048
#define D_ 512
#define H_ 8
// NORM * log2(e): scores pre-scaled so softmax uses exp2 directly.
#define NORM2_ 0.18033688011112042f

typedef __attribute__((ext_vector_type(8))) short short8;   // 8 bf16 (4 VGPRs)
typedef __attribute__((ext_vector_type(4))) float f32x4;    // MFMA C/D
#define MFMA16(a, b, c) __builtin_amdgcn_mfma_f32_16x16x32_bf16(a, b, c, 0, 0, 0)
#define EXP2(x) __builtin_amdgcn_exp2f(x)

static __device__ __forceinline__ ushort f2bf(float x) {
  union { float f; uint32_t u; } v; v.f = x;
  const uint32_t r = v.u + 0x7fffu + ((v.u >> 16) & 1u);  // RNE
  return (ushort)(r >> 16);
}

// pack two f32 -> two bf16 (RNE, native v_cvt_pk_bf16_f32); .x at low half
static __device__ __forceinline__ uint32_t pk2(float lo, float hi) {
  __hip_bfloat162 h = __float22bfloat162_rn(make_float2(lo, hi));
  return *(reinterpret_cast<uint32_t*>(&h));
}

// async global->LDS, 16B per lane. LDS dest must be wave-uniform base + lane*16.
static __device__ __forceinline__ void async16(const ushort* lds, const ushort* g) {
  __builtin_amdgcn_global_load_lds(
      (const __attribute__((address_space(1))) uint32_t*)g,
      (__attribute__((address_space(3))) uint32_t*)(ushort*)lds, 16, 0, 0);
}

// ---------------- fused prep: mask pack + all fp32->bf16 conversions ----------------
__global__ __launch_bounds__(256) void prep(const float* __restrict__ q,
                                            const int* __restrict__ mask,
                                            const float* __restrict__ wq,
                                            const float* __restrict__ wk,
                                            const float* __restrict__ wc,
                                            ushort* __restrict__ Xb,
                                            ushort* __restrict__ Wb,
                                            uint32_t* __restrict__ pk) {
  const int bx = blockIdx.x;
  if (bx < 2048) {
    const int lane = threadIdx.x & 63;
    const int wid = ((bx << 8) + threadIdx.x) >> 6;  // 8192 waves
    for (int i = wid; i < 65536; i += 8192) {        // 256-key chunks
      const int4 m = ((const int4*)mask)[(size_t)i * 64 + lane];
      uint32_t nib = (uint32_t)(m.x != 0) | ((uint32_t)(m.y != 0) << 1) |
                     ((uint32_t)(m.z != 0) << 2) | ((uint32_t)(m.w != 0) << 3);
      nib |= __shfl_xor(nib, 1) << 4;
      nib |= __shfl_xor(nib, 2) << 8;
      nib |= __shfl_xor(nib, 4) << 16;
      if ((lane & 7) == 0) pk[i * 8 + (lane >> 3)] = nib;
    }
  } else if (bx < 3072) {
    const int i = ((bx - 2048) << 8) + threadIdx.x;
    for (int j = i; j < 1048576; j += 262144) {
      const float4 v = ((const float4*)q)[j];
      uint2 o; o.x = pk2(v.x, v.y); o.y = pk2(v.z, v.w);
      ((uint2*)Xb)[j] = o;
    }
  } else {
    const int i = ((bx - 3072) << 8) + threadIdx.x;
    for (int j = i; j < 196608; j += 24576) {
      const int wi = j >> 16, off = j & 65535;
      const float* src = (wi == 0) ? wq : (wi == 1) ? wk : wc;
      const float4 v = ((const float4*)src)[off];
      uint2 o; o.x = pk2(v.x, v.y); o.y = pk2(v.z, v.w);
      ((uint2*)Wb)[j] = o;
    }
  }
}

// ---------------- 128x128 bf16 MFMA GEMM: C = X @ W^T ----------------
template <int F32OUT>
__global__ __launch_bounds__(256) void gemm128(const ushort* __restrict__ X,
                                               const ushort* __restrict__ W0,
                                               const ushort* __restrict__ W1,
                                               void* __restrict__ C0,
                                               void* __restrict__ C1,
                                               float s0, float s1) {
  const ushort* Wp = (blockIdx.z == 0) ? W0 : W1;
  void* Cp = (blockIdx.z == 0) ? C0 : C1;
  const float sc = (blockIdx.z == 0) ? s0 : s1;
  const int t = threadIdx.x;
  const int w = t >> 6, lane = t & 63, quad = lane >> 4, c = lane & 15;
  const int wm = w & 1, wn = w >> 1;
  const int n0 = blockIdx.x * 128, m0 = blockIdx.y * 128;
  __shared__ __align__(16) ushort Xs[128][64];
  __shared__ __align__(16) ushort Ws[128][64];
  f32x4 acc[4][4];
#pragma unroll
  for (int i = 0; i < 4; ++i)
#pragma unroll
    for (int j = 0; j < 4; ++j) acc[i][j] = (f32x4){0.f, 0.f, 0.f, 0.f};

  for (int k0 = 0; k0 < D_; k0 += 64) {
    __syncthreads();
#pragma unroll
    for (int g = 0; g < 4; ++g) {
      const int id = w * 256 + g * 64 + lane;
      const int row = id >> 3, lch = id & 7;
      const int gch = lch ^ (row & 7);
      async16(&Xs[row][lch * 8], X + (size_t)(m0 + row) * D_ + k0 + gch * 8);
      async16(&Ws[row][lch * 8], Wp + (size_t)(n0 + row) * D_ + k0 + gch * 8);
    }
    __syncthreads();
#pragma unroll
    for (int s = 0; s < 2; ++s) {
      short8 af[4], bt[4];
#pragma unroll
      for (int i = 0; i < 4; ++i) {
        const int rA = wn * 64 + i * 16 + c;
        af[i] = *(const short8*)&Ws[rA][(((s * 4 + quad) ^ (rA & 7)) & 7) * 8];
        const int rB = wm * 64 + i * 16 + c;
        bt[i] = *(const short8*)&Xs[rB][(((s * 4 + quad) ^ (rB & 7)) & 7) * 8];
      }
#pragma unroll
      for (int i = 0; i < 4; ++i)
#pragma unroll
        for (int j = 0; j < 4; ++j) acc[i][j] = MFMA16(af[i], bt[j], acc[i][j]);
    }
  }
#pragma unroll
  for (int i = 0; i < 4; ++i)
#pragma unroll
    for (int j = 0; j < 4; ++j) {
      const size_t off =
          (size_t)(m0 + wm * 64 + j * 16 + c) * D_ + n0 + wn * 64 + i * 16 + quad * 4;
      if (F32OUT) {
        float4 v; v.x = acc[i][j][0]; v.y = acc[i][j][1]; v.z = acc[i][j][2]; v.w = acc[i][j][3];
        *(float4*)((float*)Cp + off) = v;
      } else {
        uint2 uv;
        uv.x = pk2(acc[i][j][0] * sc, acc[i][j][1] * sc);
        uv.y = pk2(acc[i][j][2] * sc, acc[i][j][3] * sc);
        *(uint2*)((ushort*)Cp + off) = uv;
      }
    }
}

// ---------------- flash attention: bf16 MFMA, V == K, no online max ----------------
// Ping-pong LDS double-buffer: one barrier per k-tile. Stage tile kt+1 from
// prefetched registers into buf^1 AFTER computing tile kt from buf.
// l computed by ones-MFMA (all acc rows equal l); scores in log2 domain.
__global__ __launch_bounds__(256) void attn_mfma(const ushort* __restrict__ Qb,
                                                 const ushort* __restrict__ Kb,
                                                 const uint32_t* __restrict__ pk,
                                                 ushort* __restrict__ Ab) {
  const int qt = blockIdx.x, h = blockIdx.y, b = blockIdx.z;
  const int q0 = qt * 64;
  const int t = threadIdx.x;
  const int w = t >> 6, lane = t & 63, quad = lane >> 4, c = lane & 15;

  __shared__ __align__(16) ushort Ks[2][64][64];       // 16K: K rows, swizzled chunks
  __shared__ __align__(16) uint32_t KtU[2][64][32];    // 16K: V^T key-pair u32, swizzled
  __shared__ __align__(16) ushort QP[4][16][72];       // 9.2K: Qs (staging) then Pq
  ushort(*Qs)[64] = (ushort(*)[64]) & QP[0][0][0];
  ushort(*Pq)[16][72] = QP;

  // ---- stage Q once (async DMA) ----
#pragma unroll
  for (int p = 0; p < 2; ++p) {
    const int id = t + p * 256;
    const int row = id >> 3, lch = id & 7, gch = lch ^ (row & 7);
    async16(&Qs[row][lch * 8], Qb + (size_t)(b * N_ + q0 + row) * D_ + h * 64 + gch * 8);
  }
  __syncthreads();
  const int rq = (w << 4) + c;
  const short8 bq0 = *(const short8*)&Qs[rq][((quad ^ (rq & 7)) & 7) * 8];
  const short8 bq1 = *(const short8*)&Qs[rq][(((4 + quad) ^ (rq & 7)) & 7) * 8];

  short8 vones;
#pragma unroll
  for (int i = 0; i < 8; ++i) vones[i] = (short)0x3F80;  // bf16 1.0 splat

  f32x4 o[4];
#pragma unroll
  for (int i = 0; i < 4; ++i) o[i] = (f32x4){0.f, 0.f, 0.f, 0.f};
  f32x4 o5 = (f32x4){0.f, 0.f, 0.f, 0.f};  // l accumulator (ones-MFMA)

  const int kp = t >> 3, ch = t & 7;  // staging role: key-pair, d-chunk
  const int r0 = 2 * kp, r1 = r0 + 1;
  const int ksw0 = ((ch ^ (r0 & 7)) & 7) * 8, ksw1 = ((ch ^ (r1 & 7)) & 7) * 8;
  const ushort* kb0 = Kb + (size_t)(b * N_ + 2 * kp) * D_ + h * 64 + ch * 8;
  const uint32_t* pkq = pk + ((size_t)(b * N_ + q0 + (w << 4) + c) << 6);

  // ---- load + stage tile 0 into buf 0 (pre-loop) ----
  {
    const uint4 c0 = *(const uint4*)kb0;
    const uint4 c1 = *(const uint4*)(kb0 + D_);
    *(uint4*)&Ks[0][r0][ksw0] = c0;
    *(uint4*)&Ks[0][r1][ksw1] = c1;
    const uint32_t* a0 = (const uint32_t*)&c0;
    const uint32_t* a1 = (const uint32_t*)&c1;
#pragma unroll
    for (int m = 0; m < 4; ++m) {
      const uint32_t lo = __builtin_amdgcn_perm(a1[m], a0[m], 0x05040100);  // even d
      const uint32_t hi = __builtin_amdgcn_perm(a1[m], a0[m], 0x07060302);  // odd d
      const int j0 = 2 * m, j1 = 2 * m + 1;
      KtU[0][ch * 8 + j0][(kp & 3) | ((((kp >> 2) ^ j0 ^ ch) & 7) << 2)] = lo;
      KtU[0][ch * 8 + j1][(kp & 3) | ((((kp >> 2) ^ j1 ^ ch) & 7) << 2)] = hi;
    }
  }
  uint2 cm = *(const uint2*)pkq;

  const int NT = N_ / 64;
  for (int kt = 0; kt < NT; ++kt) {
    __syncthreads();  // buf[cur] fully staged; prior reads of buf[nxt] done
    const int cur = kt & 1, nxt = cur ^ 1;

    // issue global prefetch for tile kt+1 (lands during compute)
    uint4 nx0, nx1; uint2 nxm;
    const bool more = (kt + 1 < NT);
    if (more) {
      const ushort* kbn = kb0 + (size_t)(kt + 1) * 64 * D_;
      nx0 = *(const uint4*)kbn;
      nx1 = *(const uint4*)(kbn + D_);
      nxm = *(const uint2*)(pkq + (kt + 1) * 2);
    }

    // ---- S^T = K·Q^T, p = exp2(masked ? -inf : s) ----
#pragma unroll
    for (int tI = 0; tI < 4; ++tI) {
      const int rk = tI * 16 + c;
      const short8 aK0 = *(const short8*)&Ks[cur][rk][((quad ^ (rk & 7)) & 7) * 8];
      const short8 aK1 = *(const short8*)&Ks[cur][rk][(((4 + quad) ^ (rk & 7)) & 7) * 8];
      f32x4 z = (f32x4){0.f, 0.f, 0.f, 0.f};
      z = MFMA16(aK0, bq0, z);
      z = MFMA16(aK1, bq1, z);
      const uint32_t mw = (tI < 2) ? cm.x : cm.y;
      const int bb = ((tI & 1) << 4) + quad * 4;
      uint32_t pb[4];
#pragma unroll
      for (int r = 0; r < 4; ++r) {
        const float sv = ((mw >> (bb + r)) & 1u) ? -INFINITY : z[r];
        pb[r] = __float_as_uint(EXP2(sv));  // exp2(-inf) = 0
      }
      const uint32_t pw0 = __builtin_amdgcn_perm(pb[1], pb[0], 0x07060302);
      const uint32_t pw1 = __builtin_amdgcn_perm(pb[3], pb[2], 0x07060302);
      *(uint2*)&Pq[w][c][tI * 16 + quad * 4] = make_uint2(pw0, pw1);
    }

    // ---- O^T += V^T·P^T ; l via ones-MFMA ----
    const short8 bp0 = *(const short8*)&Pq[w][c][quad * 8];
    const short8 bp1 = *(const short8*)&Pq[w][c][32 + quad * 8];
    o5 = MFMA16(vones, bp0, o5);
    o5 = MFMA16(vones, bp1, o5);
#pragma unroll
    for (int dt = 0; dt < 4; ++dt) {
      const int dd = dt * 16 + c;
      const int g = (c & 7) ^ ((2 * dt + (c >> 3)) & 7);
      const short8 aV0 = *(const short8*)&KtU[cur][dd][((quad ^ g) & 7) << 2];
      const short8 aV1 = *(const short8*)&KtU[cur][dd][(((4 + quad) ^ g) & 7) << 2];
      o[dt] = MFMA16(aV0, bp0, o[dt]);
      o[dt] = MFMA16(aV1, bp1, o[dt]);
    }

    // ---- stage tile kt+1 into buf[nxt] (after compute; vmcnt drains here) ----
    if (more) {
      *(uint4*)&Ks[nxt][r0][ksw0] = nx0;
      *(uint4*)&Ks[nxt][r1][ksw1] = nx1;
      const uint32_t* a0 = (const uint32_t*)&nx0;
      const uint32_t* a1 = (const uint32_t*)&nx1;
#pragma unroll
      for (int m = 0; m < 4; ++m) {
        const uint32_t lo = __builtin_amdgcn_perm(a1[m], a0[m], 0x05040100);
        const uint32_t hi = __builtin_amdgcn_perm(a1[m], a0[m], 0x07060302);
        const int j0 = 2 * m, j1 = 2 * m + 1;
        KtU[nxt][ch * 8 + j0][(kp & 3) | ((((kp >> 2) ^ j0 ^ ch) & 7) << 2)] = lo;
        KtU[nxt][ch * 8 + j1][(kp & 3) | ((((kp >> 2) ^ j1 ^ ch) & 7) << 2)] = hi;
      }
      cm = nxm;
    }
  }

  // ---- epilogue: O^T[d][q] / l (l = o5[0], all rows equal) ----
  const float inv = 1.f / o5[0];
#pragma unroll
  for (int dt = 0; dt < 4; ++dt) {
    uint2 uv;
    uv.x = pk2(o[dt][0] * inv, o[dt][1] * inv);
    uv.y = pk2(o[dt][2] * inv, o[dt][3] * inv);
    *(uint2*)(Ab + (size_t)(b * N_ + q0 + (w << 4) + c) * D_ + h * 64 + dt * 16 + quad * 4) = uv;
  }
}

extern "C" void kernel_launch(void* const* d_in, const int* in_sizes, int n_in,
                              void* d_out, int out_size, void* d_ws, size_t ws_size,
                              hipStream_t stream) {
  const float* queries = (const float*)d_in[0];
  const int* mask = (const int*)d_in[1];
  const float* Wq = (const float*)d_in[2];
  const float* Wk = (const float*)d_in[3];
  const float* Wc = (const float*)d_in[4];
  float* out = (float*)d_out;

  const size_t nTok = (size_t)B_ * N_;
  const size_t nXD = nTok * D_;
  const size_t nW = (size_t)D_ * D_;
  ushort* Xb = (ushort*)d_ws;
  ushort* Wqb = Xb + nXD;     // Wq|Wk|Wc contiguous
  ushort* Wkb = Wqb + nW;
  ushort* Wcb = Wkb + nW;
  ushort* Qb = Wcb + nW;
  ushort* Kb = Qb + nXD;
  ushort* Ab = Kb + nXD;
  uint32_t* pk = (uint32_t*)(Ab + nXD);

  prep<<<3168, 256, 0, stream>>>(queries, mask, Wq, Wk, Wc, Xb, Wqb, pk);
  gemm128<0><<<dim3(D_ / 128, (int)(nTok / 128), 2), 256, 0, stream>>>(
      Xb, Wqb, Wkb, Qb, Kb, NORM2_, 1.0f);
  attn_mfma<<<dim3(N_ / 64, H_, B_), 256, 0, stream>>>(Qb, Kb, pk, Ab);
  gemm128<1><<<dim3(D_ / 128, (int)(nTok / 128), 1), 256, 0, stream>>>(
      Ab, Wcb, nullptr, out, nullptr, 1.0f, 1.0f);
}

// Round 10
// 211.533 us; speedup vs baseline: 2.6296x; 1.0349x over previous
//
#include <hip/hip_runtime.h>
#include <hip/hip_bf16.h>
#include <math.h>

#define B_ 4
#define N_ 2048
#define D_ 512
#define H_ 8
// NORM * log2(e): scores pre-scaled so softmax uses exp2 directly.
#define NORM2_ 0.18033688011112042f

typedef __attribute__((ext_vector_type(8))) short short8;   // 8 bf16 (4 VGPRs)
typedef __attribute__((ext_vector_type(4))) float f32x4;    // MFMA C/D
#define MFMA16(a, b, c) __builtin_amdgcn_mfma_f32_16x16x32_bf16(a, b, c, 0, 0, 0)
#define EXP2(x) __builtin_amdgcn_exp2f(x)

// pack two f32 -> two bf16 (RNE, native v_cvt_pk_bf16_f32); .x at low half
static __device__ __forceinline__ uint32_t pk2(float lo, float hi) {
  __hip_bfloat162 h = __float22bfloat162_rn(make_float2(lo, hi));
  return *(reinterpret_cast<uint32_t*>(&h));
}

// async global->LDS, 16B per lane. LDS dest must be wave-uniform base + lane*16.
static __device__ __forceinline__ void async16(const ushort* lds, const ushort* g) {
  __builtin_amdgcn_global_load_lds(
      (const __attribute__((address_space(1))) uint32_t*)g,
      (__attribute__((address_space(3))) uint32_t*)(ushort*)lds, 16, 0, 0);
}

// ---------------- fused prep: mask pack + all fp32->bf16 conversions ----------------
__global__ __launch_bounds__(256) void prep(const float* __restrict__ q,
                                            const int* __restrict__ mask,
                                            const float* __restrict__ wq,
                                            const float* __restrict__ wk,
                                            const float* __restrict__ wc,
                                            ushort* __restrict__ Xb,
                                            ushort* __restrict__ Wb,
                                            uint32_t* __restrict__ pk) {
  const int bx = blockIdx.x;
  if (bx < 2048) {
    const int lane = threadIdx.x & 63;
    const int wid = ((bx << 8) + threadIdx.x) >> 6;  // 8192 waves
    for (int i = wid; i < 65536; i += 8192) {        // 256-key chunks
      const int4 m = ((const int4*)mask)[(size_t)i * 64 + lane];
      uint32_t nib = (uint32_t)(m.x != 0) | ((uint32_t)(m.y != 0) << 1) |
                     ((uint32_t)(m.z != 0) << 2) | ((uint32_t)(m.w != 0) << 3);
      nib |= __shfl_xor(nib, 1) << 4;
      nib |= __shfl_xor(nib, 2) << 8;
      nib |= __shfl_xor(nib, 4) << 16;
      if ((lane & 7) == 0) pk[i * 8 + (lane >> 3)] = nib;
    }
  } else if (bx < 3072) {
    const int i = ((bx - 2048) << 8) + threadIdx.x;
    for (int j = i; j < 1048576; j += 262144) {
      const float4 v = ((const float4*)q)[j];
      uint2 o; o.x = pk2(v.x, v.y); o.y = pk2(v.z, v.w);
      ((uint2*)Xb)[j] = o;
    }
  } else {
    const int i = ((bx - 3072) << 8) + threadIdx.x;
    for (int j = i; j < 196608; j += 24576) {
      const int wi = j >> 16, off = j & 65535;
      const float* src = (wi == 0) ? wq : (wi == 1) ? wk : wc;
      const float4 v = ((const float4*)src)[off];
      uint2 o; o.x = pk2(v.x, v.y); o.y = pk2(v.z, v.w);
      ((uint2*)Wb)[j] = o;
    }
  }
}

// ---------------- 128x128 bf16 MFMA GEMM: C = X @ W^T ----------------
template <int F32OUT>
__global__ __launch_bounds__(256) void gemm128(const ushort* __restrict__ X,
                                               const ushort* __restrict__ W0,
                                               const ushort* __restrict__ W1,
                                               void* __restrict__ C0,
                                               void* __restrict__ C1,
                                               float s0, float s1) {
  const ushort* Wp = (blockIdx.z == 0) ? W0 : W1;
  void* Cp = (blockIdx.z == 0) ? C0 : C1;
  const float sc = (blockIdx.z == 0) ? s0 : s1;
  const int t = threadIdx.x;
  const int w = t >> 6, lane = t & 63, quad = lane >> 4, c = lane & 15;
  const int wm = w & 1, wn = w >> 1;
  const int n0 = blockIdx.x * 128, m0 = blockIdx.y * 128;
  __shared__ __align__(16) ushort Xs[128][64];
  __shared__ __align__(16) ushort Ws[128][64];
  f32x4 acc[4][4];
#pragma unroll
  for (int i = 0; i < 4; ++i)
#pragma unroll
    for (int j = 0; j < 4; ++j) acc[i][j] = (f32x4){0.f, 0.f, 0.f, 0.f};

  for (int k0 = 0; k0 < D_; k0 += 64) {
    __syncthreads();
#pragma unroll
    for (int g = 0; g < 4; ++g) {
      const int id = w * 256 + g * 64 + lane;
      const int row = id >> 3, lch = id & 7;
      const int gch = lch ^ (row & 7);
      async16(&Xs[row][lch * 8], X + (size_t)(m0 + row) * D_ + k0 + gch * 8);
      async16(&Ws[row][lch * 8], Wp + (size_t)(n0 + row) * D_ + k0 + gch * 8);
    }
    __syncthreads();
#pragma unroll
    for (int s = 0; s < 2; ++s) {
      short8 af[4], bt[4];
#pragma unroll
      for (int i = 0; i < 4; ++i) {
        const int rA = wn * 64 + i * 16 + c;
        af[i] = *(const short8*)&Ws[rA][(((s * 4 + quad) ^ (rA & 7)) & 7) * 8];
        const int rB = wm * 64 + i * 16 + c;
        bt[i] = *(const short8*)&Xs[rB][(((s * 4 + quad) ^ (rB & 7)) & 7) * 8];
      }
#pragma unroll
      for (int i = 0; i < 4; ++i)
#pragma unroll
        for (int j = 0; j < 4; ++j) acc[i][j] = MFMA16(af[i], bt[j], acc[i][j]);
    }
  }
#pragma unroll
  for (int i = 0; i < 4; ++i)
#pragma unroll
    for (int j = 0; j < 4; ++j) {
      const size_t off =
          (size_t)(m0 + wm * 64 + j * 16 + c) * D_ + n0 + wn * 64 + i * 16 + quad * 4;
      if (F32OUT) {
        float4 v; v.x = acc[i][j][0]; v.y = acc[i][j][1]; v.z = acc[i][j][2]; v.w = acc[i][j][3];
        *(float4*)((float*)Cp + off) = v;
      } else {
        uint2 uv;
        uv.x = pk2(acc[i][j][0] * sc, acc[i][j][1] * sc);
        uv.y = pk2(acc[i][j][2] * sc, acc[i][j][3] * sc);
        *(uint2*)((ushort*)Cp + off) = uv;
      }
    }
}

// ---------------- flash attention: bf16 MFMA, V == K, no online max ----------------
// Single-buffer LDS (25.6 KB, 4 blocks/CU — r8's best config) + ones-MFMA l.
// Scores in log2 domain (Q pre-scaled by NORM*log2e):
//   p = masked ? 0 : exp2(s); O += p*V; l via ones-row MFMA; epilogue O/l.
__global__ __launch_bounds__(256) void attn_mfma(const ushort* __restrict__ Qb,
                                                 const ushort* __restrict__ Kb,
                                                 const uint32_t* __restrict__ pk,
                                                 ushort* __restrict__ Ab) {
  const int qt = blockIdx.x, h = blockIdx.y, b = blockIdx.z;
  const int q0 = qt * 64;
  const int t = threadIdx.x;
  const int w = t >> 6, lane = t & 63, quad = lane >> 4, c = lane & 15;

  __shared__ __align__(16) ushort Ks[64][64];        // 8K: K rows, swizzled chunks
  __shared__ __align__(16) uint32_t KtU[64][32];     // 8K: V^T key-pair u32, swizzled
  __shared__ __align__(16) ushort QP[4][16][72];     // 9.2K: Qs (staging) then Pq
  ushort(*Qs)[64] = (ushort(*)[64]) & QP[0][0][0];
  ushort(*Pq)[16][72] = QP;

  // ---- stage Q once (async DMA) ----
#pragma unroll
  for (int p = 0; p < 2; ++p) {
    const int id = t + p * 256;
    const int row = id >> 3, lch = id & 7, gch = lch ^ (row & 7);
    async16(&Qs[row][lch * 8], Qb + (size_t)(b * N_ + q0 + row) * D_ + h * 64 + gch * 8);
  }
  __syncthreads();
  const int rq = (w << 4) + c;
  const short8 bq0 = *(const short8*)&Qs[rq][((quad ^ (rq & 7)) & 7) * 8];
  const short8 bq1 = *(const short8*)&Qs[rq][(((4 + quad) ^ (rq & 7)) & 7) * 8];

  short8 vones;
#pragma unroll
  for (int i = 0; i < 8; ++i) vones[i] = (short)0x3F80;  // bf16 1.0 splat

  f32x4 o[4];
#pragma unroll
  for (int i = 0; i < 4; ++i) o[i] = (f32x4){0.f, 0.f, 0.f, 0.f};
  f32x4 o5 = (f32x4){0.f, 0.f, 0.f, 0.f};  // l accumulator (ones-MFMA, rows identical)

  const int kp = t >> 3, ch = t & 7;  // staging role: key-pair, d-chunk
  const int r0 = 2 * kp, r1 = r0 + 1;
  const int ksw0 = ((ch ^ (r0 & 7)) & 7) * 8, ksw1 = ((ch ^ (r1 & 7)) & 7) * 8;
  const ushort* kb0 = Kb + (size_t)(b * N_ + 2 * kp) * D_ + h * 64 + ch * 8;
  const uint32_t* pkq = pk + ((size_t)(b * N_ + q0 + (w << 4) + c) << 6);

  // prefetched tile data (registers)
  uint4 c0 = *(const uint4*)kb0;
  uint4 c1 = *(const uint4*)(kb0 + D_);
  uint2 cm = *(const uint2*)pkq;
  uint4 nx0, nx1; uint2 nxm;

  const int NT = N_ / 64;
  for (int kt = 0; kt < NT; ++kt) {
    __syncthreads();  // prior tile's frag reads (and initial Qs reads) done
    // ---- stage K tile from registers (rows + u32 key-pair transpose) ----
    *(uint4*)&Ks[r0][ksw0] = c0;
    *(uint4*)&Ks[r1][ksw1] = c1;
    const uint32_t* a0 = (const uint32_t*)&c0;
    const uint32_t* a1 = (const uint32_t*)&c1;
#pragma unroll
    for (int m = 0; m < 4; ++m) {
      const uint32_t lo = __builtin_amdgcn_perm(a1[m], a0[m], 0x05040100);  // even d
      const uint32_t hi = __builtin_amdgcn_perm(a1[m], a0[m], 0x07060302);  // odd d
      const int j0 = 2 * m, j1 = 2 * m + 1;
      KtU[ch * 8 + j0][(kp & 3) | ((((kp >> 2) ^ j0 ^ ch) & 7) << 2)] = lo;
      KtU[ch * 8 + j1][(kp & 3) | ((((kp >> 2) ^ j1 ^ ch) & 7) << 2)] = hi;
    }
    __syncthreads();

    if (kt + 1 < NT) {  // prefetch next tile while computing
      const ushort* kbn = kb0 + (size_t)(kt + 1) * 64 * D_;
      nx0 = *(const uint4*)kbn;
      nx1 = *(const uint4*)(kbn + D_);
      nxm = *(const uint2*)(pkq + (kt + 1) * 2);
    }

    // ---- S^T = K·Q^T; p = masked ? 0 : exp2(s) (exp issues independent of mask chain) ----
#pragma unroll
    for (int tI = 0; tI < 4; ++tI) {
      const int rk = tI * 16 + c;
      const short8 aK0 = *(const short8*)&Ks[rk][((quad ^ (rk & 7)) & 7) * 8];
      const short8 aK1 = *(const short8*)&Ks[rk][(((4 + quad) ^ (rk & 7)) & 7) * 8];
      f32x4 z = (f32x4){0.f, 0.f, 0.f, 0.f};
      z = MFMA16(aK0, bq0, z);
      z = MFMA16(aK1, bq1, z);
      const uint32_t mw = (tI < 2) ? cm.x : cm.y;
      const int bb = ((tI & 1) << 4) + quad * 4;
      uint32_t pb[4];
#pragma unroll
      for (int r = 0; r < 4; ++r) {
        const float e = EXP2(z[r]);                       // unconditional
        pb[r] = ((mw >> (bb + r)) & 1u) ? 0u : __float_as_uint(e);
      }
      const uint32_t pw0 = __builtin_amdgcn_perm(pb[1], pb[0], 0x07060302);
      const uint32_t pw1 = __builtin_amdgcn_perm(pb[3], pb[2], 0x07060302);
      *(uint2*)&Pq[w][c][tI * 16 + quad * 4] = make_uint2(pw0, pw1);
    }

    // ---- O^T += V^T·P^T ; l via ones-MFMA ----
    const short8 bp0 = *(const short8*)&Pq[w][c][quad * 8];
    const short8 bp1 = *(const short8*)&Pq[w][c][32 + quad * 8];
    o5 = MFMA16(vones, bp0, o5);
    o5 = MFMA16(vones, bp1, o5);
#pragma unroll
    for (int dt = 0; dt < 4; ++dt) {
      const int dd = dt * 16 + c;
      const int g = (c & 7) ^ ((2 * dt + (c >> 3)) & 7);
      const short8 aV0 = *(const short8*)&KtU[dd][((quad ^ g) & 7) << 2];
      const short8 aV1 = *(const short8*)&KtU[dd][(((4 + quad) ^ g) & 7) << 2];
      o[dt] = MFMA16(aV0, bp0, o[dt]);
      o[dt] = MFMA16(aV1, bp1, o[dt]);
    }

    if (kt + 1 < NT) { c0 = nx0; c1 = nx1; cm = nxm; }
  }

  // ---- epilogue: O^T[d][q] / l (l = o5[0], all rows equal; no shuffles) ----
  const float inv = 1.f / o5[0];
#pragma unroll
  for (int dt = 0; dt < 4; ++dt) {
    uint2 uv;
    uv.x = pk2(o[dt][0] * inv, o[dt][1] * inv);
    uv.y = pk2(o[dt][2] * inv, o[dt][3] * inv);
    *(uint2*)(Ab + (size_t)(b * N_ + q0 + (w << 4) + c) * D_ + h * 64 + dt * 16 + quad * 4) = uv;
  }
}

extern "C" void kernel_launch(void* const* d_in, const int* in_sizes, int n_in,
                              void* d_out, int out_size, void* d_ws, size_t ws_size,
                              hipStream_t stream) {
  const float* queries = (const float*)d_in[0];
  const int* mask = (const int*)d_in[1];
  const float* Wq = (const float*)d_in[2];
  const float* Wk = (const float*)d_in[3];
  const float* Wc = (const float*)d_in[4];
  float* out = (float*)d_out;

  const size_t nTok = (size_t)B_ * N_;
  const size_t nXD = nTok * D_;
  const size_t nW = (size_t)D_ * D_;
  ushort* Xb = (ushort*)d_ws;
  ushort* Wqb = Xb + nXD;     // Wq|Wk|Wc contiguous
  ushort* Wkb = Wqb + nW;
  ushort* Wcb = Wkb + nW;
  ushort* Qb = Wcb + nW;
  ushort* Kb = Qb + nXD;
  ushort* Ab = Kb + nXD;
  uint32_t* pk = (uint32_t*)(Ab + nXD);

  prep<<<3168, 256, 0, stream>>>(queries, mask, Wq, Wk, Wc, Xb, Wqb, pk);
  gemm128<0><<<dim3(D_ / 128, (int)(nTok / 128), 2), 256, 0, stream>>>(
      Xb, Wqb, Wkb, Qb, Kb, NORM2_, 1.0f);
  attn_mfma<<<dim3(N_ / 64, H_, B_), 256, 0, stream>>>(Qb, Kb, pk, Ab);
  gemm128<1><<<dim3(D_ / 128, (int)(nTok / 128), 1), 256, 0, stream>>>(
      Ab, Wcb, nullptr, out, nullptr, 1.0f, 1.0f);
}